// Round 3
// baseline (349.317 us; speedup 1.0000x reference)
//
#include <hip/hip_runtime.h>

#define B_ 4
#define N_ 4096
#define C_ 256
#define M_ 2048

typedef __attribute__((ext_vector_type(8))) short short8;
typedef __attribute__((ext_vector_type(4))) float f32x4;

union U16x8 { uint4 u4; unsigned short us[8]; short8 s8; };

__device__ __forceinline__ float bf2f(unsigned short h) {
    unsigned int u = ((unsigned int)h) << 16;
    return __builtin_bit_cast(float, u);
}
__device__ __forceinline__ unsigned short f2bf(float f) {
    unsigned int u = __builtin_bit_cast(unsigned int, f);
    u += 0x7FFFu + ((u >> 16) & 1u);
    return (unsigned short)(u >> 16);
}

// ---- Fused prepass: invgn + gcm=bf16(g)[c][m] + gmc=bf16(g*invgn)[m][c] ----
// grid (M/32, B), 256 thr. Each block: 32 m-columns, all 256 c.
__global__ __launch_bounds__(256) void k_prep2(const float* __restrict__ g,
                                               unsigned short* __restrict__ gcm,
                                               unsigned short* __restrict__ gmc) {
    __shared__ float red[8][32];
    __shared__ float sInv[32];
    __shared__ unsigned short T[256 * 34];   // [c][m] tile, stride 34 (17 dw, odd) -> conflict-free transpose
    const int b = blockIdx.y, m0 = blockIdx.x * 32;
    const int tid = threadIdx.x;
    const int ml = tid & 31, cg = tid >> 5;   // cg in [0,8)
    const float* gb = g + (size_t)b * C_ * M_ + m0 + ml;
    float v[32];
    float ss = 0.f;
#pragma unroll
    for (int i = 0; i < 32; ++i) {
        v[i] = gb[(size_t)(cg * 32 + i) * M_];
        ss += v[i] * v[i];
    }
    red[cg][ml] = ss;
    __syncthreads();
    if (cg == 0) {
        float t = 0.f;
#pragma unroll
        for (int j = 0; j < 8; ++j) t += red[j][ml];
        sInv[ml] = 1.f / fmaxf(sqrtf(t), 1e-8f);
    }
    __syncthreads();
    const float inv = sInv[ml];
    unsigned short* gcmb = gcm + (size_t)b * C_ * M_ + m0 + ml;
#pragma unroll
    for (int i = 0; i < 32; ++i) {
        int c = cg * 32 + i;
        gcmb[(size_t)c * M_] = f2bf(v[i]);
        T[c * 34 + ml] = f2bf(v[i] * inv);
    }
    __syncthreads();
    unsigned short* gmcb = gmc + ((size_t)b * M_ + m0) * C_;
#pragma unroll
    for (int j = 0; j < 32; ++j) {
        int id = tid + 256 * j;
        int mr = id >> 8, cc = id & 255;
        gmcb[(size_t)mr * C_ + cc] = T[cc * 34 + mr];
    }
}

// ---------------- Main fused kernel (v3) ----------------
// Block: 256 thr / 4 waves / 64 query rows, sweeping 32 key-tiles of 64.
// GEMM1 key-split: wave w -> P[32 rows (w&1)][32 keys (w>>1)], Q A-frags in regs.
// GEMM2 c-split:   wave w -> O[all 64 rows][64 c-cols w], P shared via LDS.
// Staging: register-buffered pipeline (loads for mt+1 issued before GEMM1(mt)).
__global__ __launch_bounds__(256, 1) void k_main(
    const float* __restrict__ l,
    const unsigned short* __restrict__ gcm,    // [B][C][M] raw bf16   (GEMM2 B, k=m contiguous)
    const unsigned short* __restrict__ gmc,    // [B][M][C] normalized (GEMM1 B, k=c contiguous)
    float* __restrict__ out)
{
    // pads: row stride (dwords) % 32 ∈ {2,4} -> 2-way bank alias (free), 16B aligned
    __shared__ __align__(16) unsigned short sGmc[64 * 264];   // ghat [m][c]  33792 B (stride 528B)
    __shared__ __align__(16) unsigned short sGcm[256 * 68];   // graw [c][m]  34816 B (stride 136B)
    __shared__ __align__(16) unsigned short sP[64 * 72];      // P [n][m]      9216 B
    __shared__ float sDen[128];                               // [key-half][row]

    const int tid = threadIdx.x;
    const int w = tid >> 6;
    const int lane = tid & 63;
    const int l15 = lane & 15;
    const int quad = lane >> 4;
    const int b = blockIdx.y;
    const int row0 = blockIdx.x * 64;
    const int qrow0 = (w & 1) * 32;   // this wave's GEMM1 row base
    const int kh = w >> 1;            // this wave's GEMM1 key half

    // ---- Q: load 2 row-tiles (f32), row norms, normalize -> bf16 A-frags in regs ----
    short8 qf[2][8];
#pragma unroll
    for (int rt = 0; rt < 2; ++rt) {
        const float* lrow = l + ((size_t)b * N_ + row0 + qrow0 + rt * 16 + l15) * C_;
        U16x8 qt[8];
        float ss = 0.f;
#pragma unroll
        for (int kk = 0; kk < 8; ++kk) {
            float4 x0 = *(const float4*)(lrow + kk * 32 + quad * 8);
            float4 x1 = *(const float4*)(lrow + kk * 32 + quad * 8 + 4);
            ss += x0.x*x0.x + x0.y*x0.y + x0.z*x0.z + x0.w*x0.w;
            ss += x1.x*x1.x + x1.y*x1.y + x1.z*x1.z + x1.w*x1.w;
            qt[kk].us[0] = f2bf(x0.x); qt[kk].us[1] = f2bf(x0.y);
            qt[kk].us[2] = f2bf(x0.z); qt[kk].us[3] = f2bf(x0.w);
            qt[kk].us[4] = f2bf(x1.x); qt[kk].us[5] = f2bf(x1.y);
            qt[kk].us[6] = f2bf(x1.z); qt[kk].us[7] = f2bf(x1.w);
        }
        ss += __shfl_xor(ss, 16);
        ss += __shfl_xor(ss, 32);
        const float invl = 1.0f / fmaxf(sqrtf(ss), 1e-8f);
#pragma unroll
        for (int kk = 0; kk < 8; ++kk) {
            U16x8 t;
#pragma unroll
            for (int j = 0; j < 8; ++j) t.us[j] = f2bf(bf2f(qt[kk].us[j]) * invl);
            qf[rt][kk] = t.s8;
        }
    }

    const unsigned short* gmc_b = gmc + (size_t)b * M_ * C_;
    const unsigned short* gcm_b = gcm + (size_t)b * C_ * M_;

    uint4 rA[8], rB[8];   // staging registers
    auto load_tile = [&](int m0) {
#pragma unroll
        for (int i = 0; i < 8; ++i) {
            int id = tid + 256 * i;
            rA[i] = *(const uint4*)(gmc_b + (size_t)(m0 + (id >> 5)) * C_ + (id & 31) * 8);
            rB[i] = *(const uint4*)(gcm_b + (size_t)(id >> 3) * M_ + m0 + (id & 7) * 8);
        }
    };
    auto store_tile = [&]() {
#pragma unroll
        for (int i = 0; i < 8; ++i) {
            int id = tid + 256 * i;
            *(uint4*)&sGmc[(id >> 5) * 264 + (id & 31) * 8] = rA[i];
            *(uint4*)&sGcm[(id >> 3) * 68 + (id & 7) * 8] = rB[i];
        }
    };

    load_tile(0);
    store_tile();
    __syncthreads();

    f32x4 zero = {0.f, 0.f, 0.f, 0.f};
    f32x4 o[4][4];
#pragma unroll
    for (int i = 0; i < 4; ++i)
#pragma unroll
        for (int j = 0; j < 4; ++j) o[i][j] = zero;
    float dl[2][4] = {{0.f,0.f,0.f,0.f},{0.f,0.f,0.f,0.f}};

    for (int mt = 0; mt < 32; ++mt) {
        if (mt < 31) load_tile((mt + 1) * 64);   // in flight across GEMM1+GEMM2

        // GEMM1: P[32 rows][32 keys] for this wave's quadrant, K=256
        f32x4 sa[2][2];
        sa[0][0] = zero; sa[0][1] = zero; sa[1][0] = zero; sa[1][1] = zero;
#pragma unroll
        for (int kk = 0; kk < 8; ++kk) {
            const int off = kk * 32 + quad * 8;
#pragma unroll
            for (int ct = 0; ct < 2; ++ct) {
                short8 bb = *(const short8*)&sGmc[(kh * 32 + ct * 16 + l15) * 264 + off];
                sa[0][ct] = __builtin_amdgcn_mfma_f32_16x16x32_bf16(qf[0][kk], bb, sa[0][ct], 0, 0, 0);
                sa[1][ct] = __builtin_amdgcn_mfma_f32_16x16x32_bf16(qf[1][kk], bb, sa[1][ct], 0, 0, 0);
            }
        }
        // p = exp(cos/tau); partial row denominators; write P quadrant
#pragma unroll
        for (int rt = 0; rt < 2; ++rt)
#pragma unroll
            for (int ct = 0; ct < 2; ++ct)
#pragma unroll
                for (int r = 0; r < 4; ++r) {
                    float p = exp2f(sa[rt][ct][r] * 3.6067376022224085f);  // (1/0.4)*log2(e)
                    dl[rt][r] += p;
                    sP[(qrow0 + rt * 16 + quad * 4 + r) * 72 + kh * 32 + ct * 16 + l15] = f2bf(p);
                }
        __syncthreads();   // P complete (cross-wave read next)

        // GEMM2 c-split: O[64 rows][64 c (wave slice)] += P[64][64] * V[64][c-slice]
#pragma unroll
        for (int k2 = 0; k2 < 2; ++k2) {
            const int off = k2 * 32 + quad * 8;
            short8 a[4];
#pragma unroll
            for (int rt = 0; rt < 4; ++rt)
                a[rt] = *(const short8*)&sP[(rt * 16 + l15) * 72 + off];
#pragma unroll
            for (int ct = 0; ct < 4; ++ct) {
                short8 bb = *(const short8*)&sGcm[(w * 64 + ct * 16 + l15) * 68 + off];
#pragma unroll
                for (int rt = 0; rt < 4; ++rt)
                    o[rt][ct] = __builtin_amdgcn_mfma_f32_16x16x32_bf16(a[rt], bb, o[rt][ct], 0, 0, 0);
            }
        }
        __syncthreads();   // all reads of sP/sGmc/sGcm done
        if (mt < 31) {
            store_tile();
            __syncthreads();
        }
    }

    // ---- denominators: reduce over 16 lanes, publish per (key-half, row) ----
#pragma unroll
    for (int rt = 0; rt < 2; ++rt)
#pragma unroll
        for (int r = 0; r < 4; ++r) {
            float d = dl[rt][r];
            d += __shfl_xor(d, 1);
            d += __shfl_xor(d, 2);
            d += __shfl_xor(d, 4);
            d += __shfl_xor(d, 8);
            if (l15 == 0) sDen[kh * 64 + qrow0 + rt * 16 + quad * 4 + r] = d;
        }
    __syncthreads();

    // ---- epilogue: out = l + O/denom. Wave w writes c-cols [64w, 64w+64). ----
    const float* lb = l + ((size_t)b * N_ + row0) * C_;
    float* ob = out + ((size_t)b * N_ + row0) * C_;
#pragma unroll
    for (int rt = 0; rt < 4; ++rt) {
#pragma unroll
        for (int r = 0; r < 4; ++r) {
            const int row = rt * 16 + quad * 4 + r;
            const float inv = 1.f / (sDen[row] + sDen[64 + row]);
            const size_t rbase = (size_t)row * C_;
#pragma unroll
            for (int ct = 0; ct < 4; ++ct) {
                const int c = w * 64 + ct * 16 + l15;
                ob[rbase + c] = lb[rbase + c] + o[rt][ct][r] * inv;
            }
        }
    }
}

extern "C" void kernel_launch(void* const* d_in, const int* in_sizes, int n_in,
                              void* d_out, int out_size, void* d_ws, size_t ws_size,
                              hipStream_t stream) {
    (void)in_sizes; (void)n_in; (void)out_size; (void)ws_size;
    const float* l = (const float*)d_in[0];
    const float* g = (const float*)d_in[1];
    float* outp = (float*)d_out;

    char* ws = (char*)d_ws;
    unsigned short* gmc = (unsigned short*)ws;                                   // 4 MB (normalized, [b][m][c])
    unsigned short* gcm = (unsigned short*)(ws + (size_t)B_ * M_ * C_ * 2);      // 4 MB (raw, [b][c][m])

    k_prep2<<<dim3(M_ / 32, B_), 256, 0, stream>>>(g, gcm, gmc);
    k_main<<<dim3(N_ / 64, B_), 256, 0, stream>>>(l, gcm, gmc, outp);
}

// Round 4
// 161.237 us; speedup vs baseline: 2.1665x; 2.1665x over previous
//
#include <hip/hip_runtime.h>

#define B_ 4
#define N_ 4096
#define C_ 256
#define M_ 2048

typedef __attribute__((ext_vector_type(8))) short short8;
typedef __attribute__((ext_vector_type(4))) float f32x4;

union U16x8 { uint4 u4; unsigned short us[8]; short8 s8; };

__device__ __forceinline__ float bf2f(unsigned short h) {
    unsigned int u = ((unsigned int)h) << 16;
    return __builtin_bit_cast(float, u);
}
__device__ __forceinline__ unsigned short f2bf(float f) {
    unsigned int u = __builtin_bit_cast(unsigned int, f);
    u += 0x7FFFu + ((u >> 16) & 1u);
    return (unsigned short)(u >> 16);
}

#define GLB_AS(p) ((const __attribute__((address_space(1))) unsigned int*)(p))
#define LDS_AS(p) ((__attribute__((address_space(3))) unsigned int*)(p))

// ---- Fused prepass: invgn + gcm=bf16(g)[c][m] + gmc=bf16(g*invgn)[m][c] ----
// grid (M/32, B), 256 thr. Each block: 32 m-columns, all 256 c. Vectorized stores.
__global__ __launch_bounds__(256) void k_prep2(const float* __restrict__ g,
                                               unsigned short* __restrict__ gcm,
                                               unsigned short* __restrict__ gmc) {
    __shared__ float red[8][32];
    __shared__ float sInv[32];
    __shared__ unsigned short T[256 * 34];     // normalized [c][m], stride 34 (odd dwords)
    __shared__ unsigned short Traw[256 * 34];  // raw bf16   [c][m]
    const int b = blockIdx.y, m0 = blockIdx.x * 32;
    const int tid = threadIdx.x;
    const int ml = tid & 31, cg = tid >> 5;   // cg in [0,8)
    const float* gb = g + (size_t)b * C_ * M_ + m0 + ml;
    float v[32];
    float ss = 0.f;
#pragma unroll
    for (int i = 0; i < 32; ++i) {
        v[i] = gb[(size_t)(cg * 32 + i) * M_];
        ss += v[i] * v[i];
    }
    red[cg][ml] = ss;
    __syncthreads();
    if (cg == 0) {
        float t = 0.f;
#pragma unroll
        for (int j = 0; j < 8; ++j) t += red[j][ml];
        sInv[ml] = 1.f / fmaxf(sqrtf(t), 1e-8f);
    }
    __syncthreads();
    const float inv = sInv[ml];
#pragma unroll
    for (int i = 0; i < 32; ++i) {
        int c = cg * 32 + i;
        Traw[c * 34 + ml] = f2bf(v[i]);
        T[c * 34 + ml] = f2bf(v[i] * inv);
    }
    __syncthreads();
    // gcm: [c][m] raw, vector stores (16B)
    unsigned short* gcmb = gcm + (size_t)b * C_ * M_ + m0;
#pragma unroll
    for (int j = 0; j < 4; ++j) {
        int id = tid + 256 * j;              // 1024 chunks of 8 shorts
        int c = id >> 2, m8 = (id & 3) * 8;
        U16x8 t;
#pragma unroll
        for (int k = 0; k < 8; ++k) t.us[k] = Traw[c * 34 + m8 + k];
        *(uint4*)(gcmb + (size_t)c * M_ + m8) = t.u4;
    }
    // gmc: [m][c] normalized transpose, vector stores (16B)
    unsigned short* gmcb = gmc + ((size_t)b * M_ + m0) * C_;
#pragma unroll
    for (int j = 0; j < 4; ++j) {
        int id = tid + 256 * j;
        int mr = id >> 5, cc8 = (id & 31) * 8;
        U16x8 t;
#pragma unroll
        for (int k = 0; k < 8; ++k) t.us[k] = T[(cc8 + k) * 34 + mr];
        *(uint4*)(gmcb + (size_t)mr * C_ + cc8) = t.u4;
    }
}

// ---------------- Main fused kernel (v4) ----------------
// 256 thr / 4 waves / 64 query rows per block; wave w owns rows w*16..+15 (wave-private P,
// 1 barrier per iter). Double-buffered LDS staged by async global_load_lds (16B), XOR-swizzled
// chunks (swizzle applied on the per-lane GLOBAL source address; reads apply same XOR).
__global__ __launch_bounds__(256, 1) void k_main(
    const float* __restrict__ l,
    const unsigned short* __restrict__ gcm,    // [B][C][M] raw bf16   (GEMM2 B, k=m contig)
    const unsigned short* __restrict__ gmc,    // [B][M][C] normalized (GEMM1 B, k=c contig)
    float* __restrict__ out)
{
    __shared__ __align__(16) unsigned short sGmc[2][64 * 256];   // ghat [m][c], 32 KB x2
    __shared__ __align__(16) unsigned short sGcm[2][256 * 64];   // graw [c][m], 32 KB x2
    __shared__ __align__(16) unsigned short sP[64 * 72];         // P [n][m], padded (VALU-written)

    const int tid = threadIdx.x;
    const int w = tid >> 6;
    const int lane = tid & 63;
    const int l15 = lane & 15;
    const int quad = lane >> 4;
    const int b = blockIdx.y;
    const int row0 = blockIdx.x * 64;

    // per-lane DMA source offsets (in shorts), XOR-swizzled chunk mapping
    int goffA[8], goffB[8];
#pragma unroll
    for (int i = 0; i < 8; ++i) {
        int p = (w * 8 + i) * 64 + lane;                 // physical 16B chunk index
        int rA = p >> 5;                                 // sGmc: 32 chunks/row
        goffA[i] = rA * 256 + (((p & 31) ^ (rA & 31)) << 3);
        int rB = p >> 3;                                 // sGcm: 8 chunks/row
        goffB[i] = rB * 2048 + (((p & 7) ^ (rB & 7)) << 3);
    }

    const unsigned short* gmc_b = gmc + (size_t)b * M_ * C_;
    const unsigned short* gcm_b = gcm + (size_t)b * C_ * M_;

    auto prefetch = [&](int m0, int buf) {
#pragma unroll
        for (int i = 0; i < 8; ++i) {
            __builtin_amdgcn_global_load_lds(GLB_AS(gmc_b + (size_t)m0 * 256 + goffA[i]),
                                             LDS_AS(&sGmc[buf][(w * 8 + i) * 512]), 16, 0, 0);
            __builtin_amdgcn_global_load_lds(GLB_AS(gcm_b + (size_t)m0 + goffB[i]),
                                             LDS_AS(&sGcm[buf][(w * 8 + i) * 512]), 16, 0, 0);
        }
    };

    prefetch(0, 0);   // tile 0 in flight behind Q load/normalize

    // ---- Q: load own 16 rows (f32), row norm, normalize -> bf16 A-frags in regs ----
    const float* lrow = l + ((size_t)b * N_ + row0 + w * 16 + l15) * C_;
    U16x8 qt[8];
    float ss = 0.f;
#pragma unroll
    for (int kk = 0; kk < 8; ++kk) {
        float4 x0 = *(const float4*)(lrow + kk * 32 + quad * 8);
        float4 x1 = *(const float4*)(lrow + kk * 32 + quad * 8 + 4);
        ss += x0.x*x0.x + x0.y*x0.y + x0.z*x0.z + x0.w*x0.w;
        ss += x1.x*x1.x + x1.y*x1.y + x1.z*x1.z + x1.w*x1.w;
        qt[kk].us[0] = f2bf(x0.x); qt[kk].us[1] = f2bf(x0.y);
        qt[kk].us[2] = f2bf(x0.z); qt[kk].us[3] = f2bf(x0.w);
        qt[kk].us[4] = f2bf(x1.x); qt[kk].us[5] = f2bf(x1.y);
        qt[kk].us[6] = f2bf(x1.z); qt[kk].us[7] = f2bf(x1.w);
    }
    ss += __shfl_xor(ss, 16);
    ss += __shfl_xor(ss, 32);
    const float invl = 1.0f / fmaxf(sqrtf(ss), 1e-8f);
    short8 qf[8];
#pragma unroll
    for (int kk = 0; kk < 8; ++kk) {
        U16x8 t;
#pragma unroll
        for (int j = 0; j < 8; ++j) t.us[j] = f2bf(bf2f(qt[kk].us[j]) * invl);
        qf[kk] = t.s8;
    }

    __syncthreads();   // drains vmcnt(0): tile 0 resident

    f32x4 zero = {0.f, 0.f, 0.f, 0.f};
    f32x4 o[16];
#pragma unroll
    for (int i = 0; i < 16; ++i) o[i] = zero;
    float dl[4] = {0.f, 0.f, 0.f, 0.f};

    for (int mt = 0; mt < 32; ++mt) {
        const int cur = mt & 1;
        if (mt < 31) prefetch((mt + 1) * 64, cur ^ 1);   // async, drained at end-of-iter barrier

        // GEMM1: S(16 rows x 64 keys) over K=256, B from swizzled sGmc[cur]
        const unsigned short* gm = sGmc[cur];
        f32x4 s0 = zero, s1 = zero, s2 = zero, s3 = zero;
#pragma unroll
        for (int kk = 0; kk < 8; ++kk) {
            short8 a = qf[kk];
#pragma unroll
            for (int ct = 0; ct < 4; ++ct) {
                const int row = ct * 16 + l15;
                const int j = ((kk * 4 + quad) ^ (row & 31)) << 3;
                short8 bb = *(const short8*)&gm[row * 256 + j];
                if (ct == 0) s0 = __builtin_amdgcn_mfma_f32_16x16x32_bf16(a, bb, s0, 0, 0, 0);
                else if (ct == 1) s1 = __builtin_amdgcn_mfma_f32_16x16x32_bf16(a, bb, s1, 0, 0, 0);
                else if (ct == 2) s2 = __builtin_amdgcn_mfma_f32_16x16x32_bf16(a, bb, s2, 0, 0, 0);
                else s3 = __builtin_amdgcn_mfma_f32_16x16x32_bf16(a, bb, s3, 0, 0, 0);
            }
        }

        // p = exp(cos/tau); row denominators; write own P rows (no barrier: wave-private)
        const int prow = (w * 16 + quad * 4) * 72;
#pragma unroll
        for (int ct = 0; ct < 4; ++ct) {
            f32x4 sv = (ct == 0) ? s0 : (ct == 1) ? s1 : (ct == 2) ? s2 : s3;
#pragma unroll
            for (int r = 0; r < 4; ++r) {
                float p = exp2f(sv[r] * 3.6067376022224085f);  // (1/0.4)*log2(e)
                dl[r] += p;
                sP[prow + r * 72 + ct * 16 + l15] = f2bf(p);
            }
        }

        // GEMM2: O(16 x 256) += P(16 x 64) * V(64 x 256), B from swizzled sGcm[cur]
        const unsigned short* gc = sGcm[cur];
#pragma unroll
        for (int k2 = 0; k2 < 2; ++k2) {
            short8 a2 = *(const short8*)&sP[(w * 16 + l15) * 72 + k2 * 32 + quad * 8];
#pragma unroll
            for (int nt = 0; nt < 16; ++nt) {
                const int row = nt * 16 + l15;
                const int j = ((k2 * 4 + quad) ^ (row & 7)) << 3;
                short8 bb = *(const short8*)&gc[row * 64 + j];
                o[nt] = __builtin_amdgcn_mfma_f32_16x16x32_bf16(a2, bb, o[nt], 0, 0, 0);
            }
        }
        __syncthreads();   // readers done + prefetch drained -> swap buffers
    }

    // ---- row denominators: reduce across the 16 lanes of each quad ----
#pragma unroll
    for (int r = 0; r < 4; ++r) {
        float d = dl[r];
        d += __shfl_xor(d, 1);
        d += __shfl_xor(d, 2);
        d += __shfl_xor(d, 4);
        d += __shfl_xor(d, 8);
        dl[r] = 1.0f / d;
    }

    // ---- epilogue: out = l + O/denom (rows w*16+quad*4+r, cols nt*16+l15) ----
    const size_t obase = ((size_t)b * N_ + row0 + w * 16 + quad * 4) * C_;
#pragma unroll
    for (int nt = 0; nt < 16; ++nt) {
        int c = nt * 16 + l15;
#pragma unroll
        for (int r = 0; r < 4; ++r) {
            out[obase + (size_t)r * C_ + c] = l[obase + (size_t)r * C_ + c] + o[nt][r] * dl[r];
        }
    }
}

extern "C" void kernel_launch(void* const* d_in, const int* in_sizes, int n_in,
                              void* d_out, int out_size, void* d_ws, size_t ws_size,
                              hipStream_t stream) {
    (void)in_sizes; (void)n_in; (void)out_size; (void)ws_size;
    const float* l = (const float*)d_in[0];
    const float* g = (const float*)d_in[1];
    float* outp = (float*)d_out;

    char* ws = (char*)d_ws;
    unsigned short* gmc = (unsigned short*)ws;                                   // 4 MB (normalized, [b][m][c])
    unsigned short* gcm = (unsigned short*)(ws + (size_t)B_ * M_ * C_ * 2);      // 4 MB (raw, [b][c][m])

    k_prep2<<<dim3(M_ / 32, B_), 256, 0, stream>>>(g, gcm, gmc);
    k_main<<<dim3(N_ / 64, B_), 256, 0, stream>>>(l, gcm, gmc, outp);
}

// Round 5
// 153.479 us; speedup vs baseline: 2.2760x; 1.0505x over previous
//
#include <hip/hip_runtime.h>

#define B_ 4
#define N_ 4096
#define C_ 256
#define M_ 2048

typedef __attribute__((ext_vector_type(8))) short short8;
typedef __attribute__((ext_vector_type(4))) float f32x4;

union U16x8 { uint4 u4; unsigned short us[8]; short8 s8; };

__device__ __forceinline__ float bf2f(unsigned short h) {
    unsigned int u = ((unsigned int)h) << 16;
    return __builtin_bit_cast(float, u);
}
__device__ __forceinline__ unsigned short f2bf(float f) {
    unsigned int u = __builtin_bit_cast(unsigned int, f);
    u += 0x7FFFu + ((u >> 16) & 1u);
    return (unsigned short)(u >> 16);
}

#define GLB_AS(p) ((const __attribute__((address_space(1))) unsigned int*)(p))
#define LDS_AS(p) ((__attribute__((address_space(3))) unsigned int*)(p))

// ---- Prepass: invgn + gcm=bf16(g)[c][m] + gmc=bf16(g*invgn)[m][c], float4 loads ----
// grid (M/64, B), 256 thr; block tile = 256 c x 64 m.
__global__ __launch_bounds__(256) void k_prep3(const float* __restrict__ g,
                                               unsigned short* __restrict__ gcm,
                                               unsigned short* __restrict__ gmc) {
    __shared__ float4 red4[16][16];
    __shared__ float4 sInv4[16];
    __shared__ unsigned short T[256 * 66];   // normalized [c][m], odd-dword stride
    const int b = blockIdx.y, m0 = blockIdx.x * 64;
    const int tid = threadIdx.x;
    const int ml2 = tid & 15, cg = tid >> 4;     // ml2: m-quad, cg: c-group of 16
    const float* gb = g + (size_t)b * C_ * M_ + m0 + ml2 * 4;
    float4 v4[16];
    float4 ss = {0.f, 0.f, 0.f, 0.f};
#pragma unroll
    for (int i = 0; i < 16; ++i) {
        v4[i] = *(const float4*)(gb + (size_t)(cg * 16 + i) * M_);
        ss.x += v4[i].x * v4[i].x; ss.y += v4[i].y * v4[i].y;
        ss.z += v4[i].z * v4[i].z; ss.w += v4[i].w * v4[i].w;
    }
    red4[cg][ml2] = ss;
    __syncthreads();
    if (tid < 16) {
        float4 t = {0.f, 0.f, 0.f, 0.f};
#pragma unroll
        for (int j = 0; j < 16; ++j) {
            float4 r = red4[j][tid];
            t.x += r.x; t.y += r.y; t.z += r.z; t.w += r.w;
        }
        float4 iv;
        iv.x = 1.f / fmaxf(sqrtf(t.x), 1e-8f);
        iv.y = 1.f / fmaxf(sqrtf(t.y), 1e-8f);
        iv.z = 1.f / fmaxf(sqrtf(t.z), 1e-8f);
        iv.w = 1.f / fmaxf(sqrtf(t.w), 1e-8f);
        sInv4[tid] = iv;
    }
    __syncthreads();
    const float4 iv = sInv4[ml2];
    unsigned short* gcmb = gcm + (size_t)b * C_ * M_ + m0 + ml2 * 4;
#pragma unroll
    for (int i = 0; i < 16; ++i) {
        int c = cg * 16 + i;
        uint2 pk;
        pk.x = (unsigned)f2bf(v4[i].x) | ((unsigned)f2bf(v4[i].y) << 16);
        pk.y = (unsigned)f2bf(v4[i].z) | ((unsigned)f2bf(v4[i].w) << 16);
        *(uint2*)(gcmb + (size_t)c * M_) = pk;
        T[c * 66 + ml2 * 4 + 0] = f2bf(v4[i].x * iv.x);
        T[c * 66 + ml2 * 4 + 1] = f2bf(v4[i].y * iv.y);
        T[c * 66 + ml2 * 4 + 2] = f2bf(v4[i].z * iv.z);
        T[c * 66 + ml2 * 4 + 3] = f2bf(v4[i].w * iv.w);
    }
    __syncthreads();
    unsigned short* gmcb = gmc + ((size_t)b * M_ + m0) * C_;
#pragma unroll
    for (int j = 0; j < 8; ++j) {
        int id = j * 256 + tid;
        int mr = id >> 5, cc8 = (id & 31) * 8;
        U16x8 t;
#pragma unroll
        for (int k = 0; k < 8; ++k) t.us[k] = T[(cc8 + k) * 66 + mr];
        *(uint4*)(gmcb + (size_t)mr * C_ + cc8) = t.u4;
    }
}

// ---------------- Main fused kernel (v5) ----------------
// 256 thr / 4 waves / 64 rows; 2 blocks/CU (73.5 KB LDS). Wave (w&1)=row-half, (w>>1)=key-half
// for GEMM1 (Q x2 in regs); GEMM2 c-split (wave owns 64 channels, all rows). Single-buffered
// tiles via async global_load_lds, staggered between the 2 barriers. XOR chunk swizzle.
__global__ __launch_bounds__(256, 2) void k_main(
    const float* __restrict__ l,
    const unsigned short* __restrict__ gcm,    // [B][C][M] raw bf16   (GEMM2 B, k=m contig)
    const unsigned short* __restrict__ gmc,    // [B][M][C] normalized (GEMM1 B, k=c contig)
    float* __restrict__ out)
{
    __shared__ __align__(16) unsigned short sGmc[64 * 256];   // ghat [m][c], 32 KB
    __shared__ __align__(16) unsigned short sGcm[256 * 64];   // graw [c][m], 32 KB
    __shared__ __align__(16) unsigned short sP[64 * 72];      // P [n][m], 9216 B
    __shared__ float sDen[128];                               // [key-half][row]

    const int tid = threadIdx.x;
    const int w = tid >> 6;
    const int lane = tid & 63;
    const int l15 = lane & 15;
    const int quad = lane >> 4;
    const int b = blockIdx.y;
    const int row0 = blockIdx.x * 64;
    const int qrow0 = (w & 1) * 32;   // GEMM1 row base
    const int kh = w >> 1;            // GEMM1 key half

    // per-lane DMA source offsets (shorts), XOR-swizzled chunk mapping
    int goffA[8], goffB[8];
#pragma unroll
    for (int i = 0; i < 8; ++i) {
        int p = (w * 8 + i) * 64 + lane;
        int rA = p >> 5;
        goffA[i] = rA * 256 + (((p & 31) ^ (rA & 31)) << 3);
        int rB = p >> 3;
        goffB[i] = rB * 2048 + (((p & 7) ^ (rB & 7)) << 3);
    }

    const unsigned short* gmc_b = gmc + (size_t)b * M_ * C_;
    const unsigned short* gcm_b = gcm + (size_t)b * C_ * M_;

    auto dmaA = [&](int m0) {
#pragma unroll
        for (int i = 0; i < 8; ++i)
            __builtin_amdgcn_global_load_lds(GLB_AS(gmc_b + (size_t)m0 * 256 + goffA[i]),
                                             LDS_AS(&sGmc[(w * 8 + i) * 512]), 16, 0, 0);
    };
    auto dmaB = [&](int m0) {
#pragma unroll
        for (int i = 0; i < 8; ++i)
            __builtin_amdgcn_global_load_lds(GLB_AS(gcm_b + (size_t)m0 + goffB[i]),
                                             LDS_AS(&sGcm[(w * 8 + i) * 512]), 16, 0, 0);
    };

    dmaA(0);
    dmaB(0);

    // ---- Q: 2 row-tiles (f32), row norms, normalize -> bf16 A-frags in regs ----
    short8 qf[2][8];
#pragma unroll
    for (int rt = 0; rt < 2; ++rt) {
        const float* lrow = l + ((size_t)b * N_ + row0 + qrow0 + rt * 16 + l15) * C_;
        U16x8 qt[8];
        float ss = 0.f;
#pragma unroll
        for (int kk = 0; kk < 8; ++kk) {
            float4 x0 = *(const float4*)(lrow + kk * 32 + quad * 8);
            float4 x1 = *(const float4*)(lrow + kk * 32 + quad * 8 + 4);
            ss += x0.x*x0.x + x0.y*x0.y + x0.z*x0.z + x0.w*x0.w;
            ss += x1.x*x1.x + x1.y*x1.y + x1.z*x1.z + x1.w*x1.w;
            qt[kk].us[0] = f2bf(x0.x); qt[kk].us[1] = f2bf(x0.y);
            qt[kk].us[2] = f2bf(x0.z); qt[kk].us[3] = f2bf(x0.w);
            qt[kk].us[4] = f2bf(x1.x); qt[kk].us[5] = f2bf(x1.y);
            qt[kk].us[6] = f2bf(x1.z); qt[kk].us[7] = f2bf(x1.w);
        }
        ss += __shfl_xor(ss, 16);
        ss += __shfl_xor(ss, 32);
        const float invl = 1.0f / fmaxf(sqrtf(ss), 1e-8f);
#pragma unroll
        for (int kk = 0; kk < 8; ++kk) {
            U16x8 t;
#pragma unroll
            for (int j = 0; j < 8; ++j) t.us[j] = f2bf(bf2f(qt[kk].us[j]) * invl);
            qf[rt][kk] = t.s8;
        }
    }

    __syncthreads();   // drains DMA(tile 0)

    f32x4 zero = {0.f, 0.f, 0.f, 0.f};
    f32x4 o[4][4];
#pragma unroll
    for (int i = 0; i < 4; ++i)
#pragma unroll
        for (int j = 0; j < 4; ++j) o[i][j] = zero;
    float dl[2][4] = {{0.f,0.f,0.f,0.f},{0.f,0.f,0.f,0.f}};

    for (int mt = 0; mt < 32; ++mt) {
        // GEMM1: S[32 rows][32 keys] quadrant, K=256; B reused across 2 row-tiles
        f32x4 sa[2][2];
        sa[0][0] = zero; sa[0][1] = zero; sa[1][0] = zero; sa[1][1] = zero;
#pragma unroll
        for (int kk = 0; kk < 8; ++kk) {
#pragma unroll
            for (int ct = 0; ct < 2; ++ct) {
                const int row = kh * 32 + ct * 16 + l15;
                const int j = ((kk * 4 + quad) ^ (row & 31)) << 3;
                short8 bb = *(const short8*)&sGmc[row * 256 + j];
                sa[0][ct] = __builtin_amdgcn_mfma_f32_16x16x32_bf16(qf[0][kk], bb, sa[0][ct], 0, 0, 0);
                sa[1][ct] = __builtin_amdgcn_mfma_f32_16x16x32_bf16(qf[1][kk], bb, sa[1][ct], 0, 0, 0);
            }
        }
        // p = exp(cos/tau); partial denominators; write P quadrant
#pragma unroll
        for (int rt = 0; rt < 2; ++rt)
#pragma unroll
            for (int ct = 0; ct < 2; ++ct)
#pragma unroll
                for (int r = 0; r < 4; ++r) {
                    float p = exp2f(sa[rt][ct][r] * 3.6067376022224085f);  // (1/0.4)*log2(e)
                    dl[rt][r] += p;
                    sP[(qrow0 + rt * 16 + quad * 4 + r) * 72 + kh * 32 + ct * 16 + l15] = f2bf(p);
                }
        __syncthreads();                 // barrier A: P visible, sGmc readers done
        if (mt < 31) dmaA((mt + 1) * 64);   // covered by GEMM2, drained at barrier B

        // GEMM2 c-split: O[64 rows][64 c slice] += P[64][64] * V[64][c-slice]
#pragma unroll
        for (int k2 = 0; k2 < 2; ++k2) {
            const int off = k2 * 32 + quad * 8;
            short8 a[4];
#pragma unroll
            for (int rt = 0; rt < 4; ++rt)
                a[rt] = *(const short8*)&sP[(rt * 16 + l15) * 72 + off];
#pragma unroll
            for (int ct = 0; ct < 4; ++ct) {
                const int crow = w * 64 + ct * 16 + l15;
                const int j = ((k2 * 4 + quad) ^ (crow & 7)) << 3;
                short8 bb = *(const short8*)&sGcm[crow * 64 + j];
#pragma unroll
                for (int rt = 0; rt < 4; ++rt)
                    o[rt][ct] = __builtin_amdgcn_mfma_f32_16x16x32_bf16(a[rt], bb, o[rt][ct], 0, 0, 0);
            }
        }
        __syncthreads();                 // barrier B: sGcm/sP readers done, dmaA drained
        if (mt < 31) dmaB((mt + 1) * 64);   // covered by next GEMM1, drained at barrier A
    }

    // ---- denominators: reduce over 16 lanes, publish per (key-half, row) ----
#pragma unroll
    for (int rt = 0; rt < 2; ++rt)
#pragma unroll
        for (int r = 0; r < 4; ++r) {
            float d = dl[rt][r];
            d += __shfl_xor(d, 1);
            d += __shfl_xor(d, 2);
            d += __shfl_xor(d, 4);
            d += __shfl_xor(d, 8);
            if (l15 == 0) sDen[kh * 64 + qrow0 + rt * 16 + quad * 4 + r] = d;
        }
    __syncthreads();

    // ---- epilogue: out = l + O/denom. Wave w writes c-cols [64w, 64w+64). ----
    const float* lb = l + ((size_t)b * N_ + row0) * C_;
    float* ob = out + ((size_t)b * N_ + row0) * C_;
#pragma unroll
    for (int rt = 0; rt < 4; ++rt) {
#pragma unroll
        for (int r = 0; r < 4; ++r) {
            const int row = rt * 16 + quad * 4 + r;
            const float inv = 1.f / (sDen[row] + sDen[64 + row]);
            const size_t rbase = (size_t)row * C_;
#pragma unroll
            for (int ct = 0; ct < 4; ++ct) {
                const int c = w * 64 + ct * 16 + l15;
                ob[rbase + c] = lb[rbase + c] + o[rt][ct][r] * inv;
            }
        }
    }
}

extern "C" void kernel_launch(void* const* d_in, const int* in_sizes, int n_in,
                              void* d_out, int out_size, void* d_ws, size_t ws_size,
                              hipStream_t stream) {
    (void)in_sizes; (void)n_in; (void)out_size; (void)ws_size;
    const float* l = (const float*)d_in[0];
    const float* g = (const float*)d_in[1];
    float* outp = (float*)d_out;

    char* ws = (char*)d_ws;
    unsigned short* gmc = (unsigned short*)ws;                                   // 4 MB (normalized, [b][m][c])
    unsigned short* gcm = (unsigned short*)(ws + (size_t)B_ * M_ * C_ * 2);      // 4 MB (raw, [b][c][m])

    k_prep3<<<dim3(M_ / 64, B_), 256, 0, stream>>>(g, gcm, gmc);
    k_main<<<dim3(N_ / 64, B_), 256, 0, stream>>>(l, gcm, gmc, outp);
}

// Round 6
// 142.394 us; speedup vs baseline: 2.4532x; 1.0779x over previous
//
#include <hip/hip_runtime.h>

#define B_ 4
#define N_ 4096
#define C_ 256
#define M_ 2048

typedef __attribute__((ext_vector_type(8))) short short8;
typedef __attribute__((ext_vector_type(4))) float f32x4;

union U16x8 { uint4 u4; unsigned short us[8]; short8 s8; };

__device__ __forceinline__ float bf2f(unsigned short h) {
    unsigned int u = ((unsigned int)h) << 16;
    return __builtin_bit_cast(float, u);
}
__device__ __forceinline__ unsigned short f2bf(float f) {
    unsigned int u = __builtin_bit_cast(unsigned int, f);
    u += 0x7FFFu + ((u >> 16) & 1u);
    return (unsigned short)(u >> 16);
}

#define GLB_AS(p) ((const __attribute__((address_space(1))) unsigned int*)(p))
#define LDS_AS(p) ((__attribute__((address_space(3))) unsigned int*)(p))

// ---- Prepass A: invgn[b][m] = 1/max(||g[b][:,m]||, 1e-8). grid (M/64, B), 256 thr ----
__global__ __launch_bounds__(256) void k_norm(const float* __restrict__ g,
                                              float* __restrict__ invgn) {
    __shared__ float red[4][64];
    const int b = blockIdx.y, m0 = blockIdx.x * 64;
    const int tid = threadIdx.x;
    const int ml = tid & 63, cq = tid >> 6;     // cq in [0,4)
    const float* gb = g + (size_t)b * C_ * M_ + m0 + ml;
    float ss = 0.f;
#pragma unroll 8
    for (int i = 0; i < 64; ++i) {
        float v = gb[(size_t)(cq * 64 + i) * M_];
        ss += v * v;
    }
    red[cq][ml] = ss;
    __syncthreads();
    if (cq == 0) {
        float t = red[0][ml] + red[1][ml] + red[2][ml] + red[3][ml];
        invgn[b * M_ + m0 + ml] = 1.f / fmaxf(sqrtf(t), 1e-8f);
    }
}

// ---- Prepass B: gcm = bf16(g)[c][m]; gmc = bf16(g*invgn)[m][c]. grid (M/64, C/64, B) ----
__global__ __launch_bounds__(256) void k_cast(const float* __restrict__ g,
                                              const float* __restrict__ invgn,
                                              unsigned short* __restrict__ gcm,
                                              unsigned short* __restrict__ gmc) {
    __shared__ unsigned short T[64 * 66];   // normalized [c][m] tile, odd-dword stride
    __shared__ float sInv[64];
    const int b = blockIdx.z, c0 = blockIdx.y * 64, m0 = blockIdx.x * 64;
    const int tid = threadIdx.x;
    if (tid < 64) sInv[tid] = invgn[b * M_ + m0 + tid];
    __syncthreads();
    const float* gbase = g + ((size_t)b * C_ + c0) * M_ + m0;
    unsigned short* gcmb = gcm + ((size_t)b * C_ + c0) * M_ + m0;
#pragma unroll
    for (int j = 0; j < 4; ++j) {
        int id = tid + 256 * j;                 // 1024 float4-chunks
        int ci = id >> 4, mq = (id & 15) * 4;
        float4 v = *(const float4*)(gbase + (size_t)ci * M_ + mq);
        uint2 pk;
        pk.x = (unsigned)f2bf(v.x) | ((unsigned)f2bf(v.y) << 16);
        pk.y = (unsigned)f2bf(v.z) | ((unsigned)f2bf(v.w) << 16);
        *(uint2*)(gcmb + (size_t)ci * M_ + mq) = pk;
        T[ci * 66 + mq + 0] = f2bf(v.x * sInv[mq + 0]);
        T[ci * 66 + mq + 1] = f2bf(v.y * sInv[mq + 1]);
        T[ci * 66 + mq + 2] = f2bf(v.z * sInv[mq + 2]);
        T[ci * 66 + mq + 3] = f2bf(v.w * sInv[mq + 3]);
    }
    __syncthreads();
    unsigned short* gmcb = gmc + ((size_t)b * M_ + m0) * C_ + c0;
#pragma unroll
    for (int j = 0; j < 2; ++j) {
        int id = tid + 256 * j;                 // 512 8-short chunks
        int mr = id >> 3, cc8 = (id & 7) * 8;
        U16x8 t;
#pragma unroll
        for (int k = 0; k < 8; ++k) t.us[k] = T[(cc8 + k) * 66 + mr];
        *(uint4*)(gmcb + (size_t)mr * C_ + cc8) = t.u4;
    }
}

// ---------------- Main fused kernel (v6) ----------------
// 32 query rows / block, grid 512 -> 2 blocks/CU (TLP: one block's MFMA fills the other's
// barrier/DMA stalls). 4 waves: GEMM1 wave=(row-half 16, key-half 32); GEMM2 c-split
// (wave owns 64 channels, all 32 rows). Async global_load_lds staging, XOR chunk swizzle,
// DMA issue staggered between the two barriers.
__global__ __launch_bounds__(256, 2) void k_main(
    const float* __restrict__ l,
    const unsigned short* __restrict__ gcm,    // [B][C][M] raw bf16   (GEMM2 B, k=m contig)
    const unsigned short* __restrict__ gmc,    // [B][M][C] normalized (GEMM1 B, k=c contig)
    float* __restrict__ out)
{
    __shared__ __align__(16) unsigned short sGmc[64 * 256];   // ghat [m][c], 32 KB
    __shared__ __align__(16) unsigned short sGcm[256 * 64];   // graw [c][m], 32 KB
    __shared__ __align__(16) unsigned short sP[32 * 72];      // P [n][m], 4608 B
    __shared__ float sDen[2][32];                             // [key-half][row]

    const int tid = threadIdx.x;
    const int w = tid >> 6;
    const int lane = tid & 63;
    const int l15 = lane & 15;
    const int quad = lane >> 4;
    const int b = blockIdx.y;
    const int row0 = blockIdx.x * 32;
    const int rh = (w & 1) * 16;      // GEMM1 row base (within block)
    const int kh = w >> 1;            // GEMM1 key half

    // per-lane DMA source offsets (shorts), XOR-swizzled chunk mapping
    int goffA[8], goffB[8];
#pragma unroll
    for (int i = 0; i < 8; ++i) {
        int p = (w * 8 + i) * 64 + lane;
        int rA = p >> 5;
        goffA[i] = rA * 256 + (((p & 31) ^ (rA & 31)) << 3);
        int rB = p >> 3;
        goffB[i] = rB * 2048 + (((p & 7) ^ (rB & 7)) << 3);
    }

    const unsigned short* gmc_b = gmc + (size_t)b * M_ * C_;
    const unsigned short* gcm_b = gcm + (size_t)b * C_ * M_;

    auto dmaA = [&](int m0) {
#pragma unroll
        for (int i = 0; i < 8; ++i)
            __builtin_amdgcn_global_load_lds(GLB_AS(gmc_b + (size_t)m0 * 256 + goffA[i]),
                                             LDS_AS(&sGmc[(w * 8 + i) * 512]), 16, 0, 0);
    };
    auto dmaB = [&](int m0) {
#pragma unroll
        for (int i = 0; i < 8; ++i)
            __builtin_amdgcn_global_load_lds(GLB_AS(gcm_b + (size_t)m0 + goffB[i]),
                                             LDS_AS(&sGcm[(w * 8 + i) * 512]), 16, 0, 0);
    };

    dmaA(0);
    dmaB(0);

    // ---- Q: my 16 rows (f32), row norm, normalize -> bf16 A-frags in regs ----
    const float* lrow = l + ((size_t)b * N_ + row0 + rh + l15) * C_;
    U16x8 qt[8];
    float ss = 0.f;
#pragma unroll
    for (int kk = 0; kk < 8; ++kk) {
        float4 x0 = *(const float4*)(lrow + kk * 32 + quad * 8);
        float4 x1 = *(const float4*)(lrow + kk * 32 + quad * 8 + 4);
        ss += x0.x*x0.x + x0.y*x0.y + x0.z*x0.z + x0.w*x0.w;
        ss += x1.x*x1.x + x1.y*x1.y + x1.z*x1.z + x1.w*x1.w;
        qt[kk].us[0] = f2bf(x0.x); qt[kk].us[1] = f2bf(x0.y);
        qt[kk].us[2] = f2bf(x0.z); qt[kk].us[3] = f2bf(x0.w);
        qt[kk].us[4] = f2bf(x1.x); qt[kk].us[5] = f2bf(x1.y);
        qt[kk].us[6] = f2bf(x1.z); qt[kk].us[7] = f2bf(x1.w);
    }
    ss += __shfl_xor(ss, 16);
    ss += __shfl_xor(ss, 32);
    const float invl = 1.0f / fmaxf(sqrtf(ss), 1e-8f);
    short8 qf[8];
#pragma unroll
    for (int kk = 0; kk < 8; ++kk) {
        U16x8 t;
#pragma unroll
        for (int j = 0; j < 8; ++j) t.us[j] = f2bf(bf2f(qt[kk].us[j]) * invl);
        qf[kk] = t.s8;
    }

    __syncthreads();   // drains DMA(tile 0)

    f32x4 zero = {0.f, 0.f, 0.f, 0.f};
    f32x4 o[2][4];     // [row-tile][c-tile] for my 64-channel slice
#pragma unroll
    for (int i = 0; i < 2; ++i)
#pragma unroll
        for (int j = 0; j < 4; ++j) o[i][j] = zero;
    float dl[4] = {0.f, 0.f, 0.f, 0.f};

    for (int mt = 0; mt < 32; ++mt) {
        // GEMM1: S[16 rows][32 keys] (my quadrant), K=256
        f32x4 sa[2];
        sa[0] = zero; sa[1] = zero;
#pragma unroll
        for (int kk = 0; kk < 8; ++kk) {
#pragma unroll
            for (int ct = 0; ct < 2; ++ct) {
                const int row = kh * 32 + ct * 16 + l15;
                const int j = ((kk * 4 + quad) ^ (row & 31)) << 3;
                short8 bb = *(const short8*)&sGmc[row * 256 + j];
                sa[ct] = __builtin_amdgcn_mfma_f32_16x16x32_bf16(qf[kk], bb, sa[ct], 0, 0, 0);
            }
        }
        // p = exp(cos/tau); partial denominators; write P quadrant
#pragma unroll
        for (int ct = 0; ct < 2; ++ct)
#pragma unroll
            for (int r = 0; r < 4; ++r) {
                float p = exp2f(sa[ct][r] * 3.6067376022224085f);  // (1/0.4)*log2(e)
                dl[r] += p;
                sP[(rh + quad * 4 + r) * 72 + kh * 32 + ct * 16 + l15] = f2bf(p);
            }
        __syncthreads();                    // barrier A: P visible, sGmc readers done
        if (mt < 31) dmaA((mt + 1) * 64);   // covered by GEMM2, drained at barrier B

        // GEMM2 c-split: O[32 rows][64 c slice] += P[32][64] * V[64][c-slice]
#pragma unroll
        for (int k2 = 0; k2 < 2; ++k2) {
            const int off = k2 * 32 + quad * 8;
            short8 a[2];
#pragma unroll
            for (int rt = 0; rt < 2; ++rt)
                a[rt] = *(const short8*)&sP[(rt * 16 + l15) * 72 + off];
#pragma unroll
            for (int ct = 0; ct < 4; ++ct) {
                const int crow = w * 64 + ct * 16 + l15;
                const int j = ((k2 * 4 + quad) ^ (crow & 7)) << 3;
                short8 bb = *(const short8*)&sGcm[crow * 64 + j];
#pragma unroll
                for (int rt = 0; rt < 2; ++rt)
                    o[rt][ct] = __builtin_amdgcn_mfma_f32_16x16x32_bf16(a[rt], bb, o[rt][ct], 0, 0, 0);
            }
        }
        __syncthreads();                    // barrier B: sGcm/sP readers done, dmaA drained
        if (mt < 31) dmaB((mt + 1) * 64);   // covered by next GEMM1, drained at barrier A
    }

    // ---- denominators: reduce over 16 lanes, publish per (key-half, row) ----
#pragma unroll
    for (int r = 0; r < 4; ++r) {
        float d = dl[r];
        d += __shfl_xor(d, 1);
        d += __shfl_xor(d, 2);
        d += __shfl_xor(d, 4);
        d += __shfl_xor(d, 8);
        if (l15 == 0) sDen[kh][rh + quad * 4 + r] = d;
    }
    __syncthreads();

    // ---- epilogue: out = l + O/denom. Wave w writes c-cols [64w, 64w+64). ----
    const float* lb = l + ((size_t)b * N_ + row0) * C_;
    float* ob = out + ((size_t)b * N_ + row0) * C_;
#pragma unroll
    for (int rt = 0; rt < 2; ++rt) {
#pragma unroll
        for (int r = 0; r < 4; ++r) {
            const int row = rt * 16 + quad * 4 + r;
            const float inv = 1.f / (sDen[0][row] + sDen[1][row]);
            const size_t rbase = (size_t)row * C_;
#pragma unroll
            for (int ct = 0; ct < 4; ++ct) {
                const int c = w * 64 + ct * 16 + l15;
                ob[rbase + c] = lb[rbase + c] + o[rt][ct][r] * inv;
            }
        }
    }
}

extern "C" void kernel_launch(void* const* d_in, const int* in_sizes, int n_in,
                              void* d_out, int out_size, void* d_ws, size_t ws_size,
                              hipStream_t stream) {
    (void)in_sizes; (void)n_in; (void)out_size; (void)ws_size;
    const float* l = (const float*)d_in[0];
    const float* g = (const float*)d_in[1];
    float* outp = (float*)d_out;

    char* ws = (char*)d_ws;
    unsigned short* gmc = (unsigned short*)ws;                                   // 4 MB (normalized, [b][m][c])
    unsigned short* gcm = (unsigned short*)(ws + (size_t)B_ * M_ * C_ * 2);      // 4 MB (raw, [b][c][m])
    float* invgn = (float*)(ws + 2 * (size_t)B_ * M_ * C_ * 2);                  // 32 KB

    k_norm<<<dim3(M_ / 64, B_), 256, 0, stream>>>(g, invgn);
    k_cast<<<dim3(M_ / 64, C_ / 64, B_), 256, 0, stream>>>(g, invgn, gcm, gmc);
    k_main<<<dim3(N_ / 32, B_), 256, 0, stream>>>(l, gcm, gmc, outp);
}